// Round 1
// baseline (1204.601 us; speedup 1.0000x reference)
//
#include <hip/hip_runtime.h>
#include <math.h>

#define NN 50000
#define RR 8
#define HH 128
#define LL 32
#define EE 1600000

// ---- count edges per (dst, relation) ----
__global__ void count_kernel(const int* __restrict__ ei, const int* __restrict__ et,
                             unsigned* __restrict__ cnt) {
    int e = blockIdx.x * blockDim.x + threadIdx.x;
    if (e >= EE) return;
    int dst = ei[EE + e];
    int r = et[e];
    atomicAdd(&cnt[dst * RR + r], 1u);
}

// ---- cnt -> 1/max(cnt,1), in place (uint -> float) ----
__global__ void inv_kernel(float* __restrict__ inv) {
    int i = blockIdx.x * blockDim.x + threadIdx.x;
    if (i >= NN * RR) return;
    unsigned c = ((const unsigned*)inv)[i];
    inv[i] = c ? 1.0f / (float)c : 0.0f;
}

// ---- layer 1 scatter: xacc[dst,h] += w1[et,src,h] * inv[dst,et] ----
// one thread per (edge, h); 2 edges per 256-thread block
__global__ void l1_agg_kernel(const int* __restrict__ ei, const int* __restrict__ et,
                              const float* __restrict__ w1, const float* __restrict__ inv,
                              float* __restrict__ xacc) {
    int idx = blockIdx.x * blockDim.x + threadIdx.x;  // E*H = 204.8M < 2^31
    int e = idx >> 7;
    int h = idx & 127;
    if (e >= EE) return;
    int src = ei[e];
    int dst = ei[EE + e];
    int r = et[e];
    float ic = inv[dst * RR + r];
    float v = w1[(size_t)r * (NN * HH) + (size_t)src * HH + h] * ic;
    atomicAdd(&xacc[(size_t)dst * HH + h], v);
}

// ---- x = relu(xacc + root1 + bias1) in place ----
__global__ void relu_kernel(float* __restrict__ xacc, const float* __restrict__ root1,
                            const float* __restrict__ bias1) {
    int i = blockIdx.x * blockDim.x + threadIdx.x;
    if (i >= NN * HH) return;
    float v = xacc[i] + root1[i] + bias1[i & 127];
    xacc[i] = v > 0.f ? v : 0.f;
}

// ---- xw[n,r,l] = sum_h x[n,h] * w2[r,h,l]; one node per 256-thread block ----
__global__ void xw_kernel(const float* __restrict__ x, const float* __restrict__ w2,
                          float* __restrict__ xw) {
    __shared__ float xs[HH];
    int n = blockIdx.x;
    int t = threadIdx.x;
    if (t < HH) xs[t] = x[(size_t)n * HH + t];
    __syncthreads();
    int r = t >> 5, l = t & 31;
    const float* wp = w2 + r * HH * LL + l;
    float acc = 0.f;
#pragma unroll
    for (int h = 0; h < HH; ++h) acc += xs[h] * wp[h * LL];
    xw[(size_t)n * (RR * LL) + t] = acc;
}

// ---- layer 2 scatter: out[dst,l] += xw[src,et,l] * inv[dst,et] ----
__global__ void l2_agg_kernel(const int* __restrict__ ei, const int* __restrict__ et,
                              const float* __restrict__ xw, const float* __restrict__ inv,
                              float* __restrict__ out) {
    int idx = blockIdx.x * blockDim.x + threadIdx.x;  // E*L = 51.2M
    int e = idx >> 5;
    int l = idx & 31;
    if (e >= EE) return;
    int src = ei[e];
    int dst = ei[EE + e];
    int r = et[e];
    float v = xw[(size_t)src * (RR * LL) + r * LL + l] * inv[dst * RR + r];
    atomicAdd(&out[dst * LL + l], v);
}

// ---- out = sigmoid(out + x@root2 + bias2) in place ----
__global__ void final_kernel(float* __restrict__ out, const float* __restrict__ x,
                             const float* __restrict__ root2, const float* __restrict__ bias2) {
    int i = blockIdx.x * blockDim.x + threadIdx.x;
    if (i >= NN * LL) return;
    int n = i >> 5, l = i & 31;
    float acc = out[i] + bias2[l];
    const float* xp = x + (size_t)n * HH;
#pragma unroll 8
    for (int h = 0; h < HH; ++h) acc += xp[h] * root2[h * LL + l];
    out[i] = 1.f / (1.f + expf(-acc));
}

extern "C" void kernel_launch(void* const* d_in, const int* in_sizes, int n_in,
                              void* d_out, int out_size, void* d_ws, size_t ws_size,
                              hipStream_t stream) {
    const float* w1    = (const float*)d_in[0];
    const float* root1 = (const float*)d_in[1];
    const float* bias1 = (const float*)d_in[2];
    const float* w2    = (const float*)d_in[3];
    const float* root2 = (const float*)d_in[4];
    const float* bias2 = (const float*)d_in[5];
    const int*   ei    = (const int*)d_in[6];
    const int*   et    = (const int*)d_in[7];
    float* out = (float*)d_out;

    float* inv  = (float*)d_ws;                   // N*R floats  (1.6 MB)
    float* xacc = inv + NN * RR;                  // N*H floats  (25.6 MB)
    float* xw   = xacc + (size_t)NN * HH;         // N*R*L floats (51.2 MB)

    hipMemsetAsync(inv, 0, (size_t)NN * RR * sizeof(float), stream);
    hipMemsetAsync(xacc, 0, (size_t)NN * HH * sizeof(float), stream);
    hipMemsetAsync(out, 0, (size_t)NN * LL * sizeof(float), stream);

    count_kernel<<<(EE + 255) / 256, 256, 0, stream>>>(ei, et, (unsigned*)inv);
    inv_kernel<<<(NN * RR + 255) / 256, 256, 0, stream>>>(inv);
    l1_agg_kernel<<<(int)(((long long)EE * HH + 255) / 256), 256, 0, stream>>>(ei, et, w1, inv, xacc);
    relu_kernel<<<(NN * HH + 255) / 256, 256, 0, stream>>>(xacc, root1, bias1);
    xw_kernel<<<NN, 256, 0, stream>>>(xacc, w2, xw);
    l2_agg_kernel<<<(int)(((long long)EE * LL + 255) / 256), 256, 0, stream>>>(ei, et, xw, inv, out);
    final_kernel<<<(NN * LL + 255) / 256, 256, 0, stream>>>(out, xacc, root2, bias2);
}

// Round 2
// 723.598 us; speedup vs baseline: 1.6647x; 1.6647x over previous
//
#include <hip/hip_runtime.h>
#include <math.h>

#define NN 50000
#define RR 8
#define HH 128
#define LL 32
#define EE 1600000

// ---- count edges per (dst, relation) ----
__global__ void count_kernel(const int* __restrict__ ei, const int* __restrict__ et,
                             unsigned* __restrict__ cnt) {
    int e = blockIdx.x * blockDim.x + threadIdx.x;
    if (e >= EE) return;
    int dst = ei[EE + e];
    int r = et[e];
    atomicAdd(&cnt[dst * RR + r], 1u);
}

// ---- per node: inv[n,r] = 1/max(cnt,1) in place; cnt_n[n] = total degree ----
__global__ void inv_total_kernel(unsigned* __restrict__ cnt_nr, float* __restrict__ inv,
                                 unsigned* __restrict__ cnt_n) {
    int n = blockIdx.x * blockDim.x + threadIdx.x;
    if (n >= NN) return;
    unsigned tot = 0;
#pragma unroll
    for (int r = 0; r < RR; ++r) {
        unsigned c = cnt_nr[n * RR + r];
        tot += c;
        inv[n * RR + r] = c ? 1.0f / (float)c : 0.0f;
    }
    cnt_n[n] = tot;
}

// ---- exclusive scan, 3 kernels (chunks of 256) ----
__global__ void scan_blocks(const unsigned* __restrict__ cnt_n, unsigned* __restrict__ node_off,
                            unsigned* __restrict__ bsums) {
    __shared__ unsigned s[256];
    int t = threadIdx.x, g = blockIdx.x * 256 + t;
    unsigned v = (g < NN) ? cnt_n[g] : 0;
    s[t] = v; __syncthreads();
    for (int off = 1; off < 256; off <<= 1) {
        unsigned u = (t >= off) ? s[t - off] : 0; __syncthreads();
        if (t >= off) s[t] += u; __syncthreads();
    }
    if (g < NN) node_off[g] = s[t] - v;
    if (t == 255) bsums[blockIdx.x] = s[255];
}

__global__ void scan_top(unsigned* __restrict__ bsums, int nb) {
    __shared__ unsigned s[256];
    int t = threadIdx.x;
    unsigned v = (t < nb) ? bsums[t] : 0;
    s[t] = v; __syncthreads();
    for (int off = 1; off < 256; off <<= 1) {
        unsigned u = (t >= off) ? s[t - off] : 0; __syncthreads();
        if (t >= off) s[t] += u; __syncthreads();
    }
    if (t < nb) bsums[t] = s[t] - v;
}

__global__ void scan_add(unsigned* __restrict__ node_off, const unsigned* __restrict__ bsums,
                         unsigned* __restrict__ cursor) {
    int g = blockIdx.x * 256 + threadIdx.x;
    if (g < NN) {
        unsigned o = node_off[g] + bsums[g >> 8];
        node_off[g] = o;
        cursor[g] = o;
    }
    if (g == 0) node_off[NN] = EE;
}

// ---- scatter edges into dst-sorted order, packed key src | (r<<16) ----
__global__ void scatter_kernel(const int* __restrict__ ei, const int* __restrict__ et,
                               unsigned* __restrict__ cursor, unsigned* __restrict__ srcr) {
    int e = blockIdx.x * blockDim.x + threadIdx.x;
    if (e >= EE) return;
    int src = ei[e], dst = ei[EE + e], r = et[e];
    unsigned p = atomicAdd(&cursor[dst], 1u);
    srcr[p] = (unsigned)src | ((unsigned)r << 16);
}

// ---- layer 1: one wave per node, gather w1 rows, fused root1+bias1+relu ----
__global__ __launch_bounds__(256) void l1_gather(const unsigned* __restrict__ node_off,
                                                 const unsigned* __restrict__ srcr,
                                                 const float* __restrict__ inv,
                                                 const float* __restrict__ w1,
                                                 const float* __restrict__ root1,
                                                 const float* __restrict__ bias1,
                                                 float* __restrict__ x) {
    int wid = threadIdx.x >> 6, lane = threadIdx.x & 63;
    int n = blockIdx.x * 4 + wid;
    if (n >= NN) return;
    int beg = node_off[n], end = node_off[n + 1];
    float ax = 0.f, ay = 0.f;
    for (int e = beg; e < end; ++e) {
        unsigned k = srcr[e];
        unsigned src = k & 0xFFFFu, r = k >> 16;
        float sc = inv[n * RR + r];
        float2 v = ((const float2*)(w1 + ((size_t)r * NN + src) * HH))[lane];
        ax += v.x * sc;
        ay += v.y * sc;
    }
    float2 rt = ((const float2*)(root1 + (size_t)n * HH))[lane];
    float o0 = ax + rt.x + bias1[2 * lane];
    float o1 = ay + rt.y + bias1[2 * lane + 1];
    float2 res;
    res.x = o0 > 0.f ? o0 : 0.f;
    res.y = o1 > 0.f ? o1 : 0.f;
    ((float2*)(x + (size_t)n * HH))[lane] = res;
}

// ---- xw[n,r,l] = sum_h x[n,h] * w2[r,h,l]; one node per 256-thread block ----
__global__ void xw_kernel(const float* __restrict__ x, const float* __restrict__ w2,
                          float* __restrict__ xw) {
    __shared__ float xs[HH];
    int n = blockIdx.x;
    int t = threadIdx.x;
    if (t < HH) xs[t] = x[(size_t)n * HH + t];
    __syncthreads();
    int r = t >> 5, l = t & 31;
    const float* wp = w2 + r * HH * LL + l;
    float acc = 0.f;
#pragma unroll
    for (int h = 0; h < HH; ++h) acc += xs[h] * wp[h * LL];
    xw[(size_t)n * (RR * LL) + t] = acc;
}

// ---- layer 2: 32 threads per node, gather xw rows, fused x@root2+bias2+sigmoid ----
__global__ __launch_bounds__(256) void l2_gather(const unsigned* __restrict__ node_off,
                                                 const unsigned* __restrict__ srcr,
                                                 const float* __restrict__ inv,
                                                 const float* __restrict__ xw,
                                                 const float* __restrict__ x,
                                                 const float* __restrict__ root2,
                                                 const float* __restrict__ bias2,
                                                 float* __restrict__ out) {
    int gidx = threadIdx.x >> 5, l = threadIdx.x & 31;
    int n = blockIdx.x * 8 + gidx;
    if (n >= NN) return;
    int beg = node_off[n], end = node_off[n + 1];
    float acc = bias2[l];
    for (int e = beg; e < end; ++e) {
        unsigned k = srcr[e];
        unsigned src = k & 0xFFFFu, r = k >> 16;
        acc += xw[((size_t)src * RR + r) * LL + l] * inv[n * RR + r];
    }
    const float* xp = x + (size_t)n * HH;
#pragma unroll 8
    for (int h = 0; h < HH; ++h) acc += xp[h] * root2[h * LL + l];
    out[n * LL + l] = 1.0f / (1.0f + expf(-acc));
}

extern "C" void kernel_launch(void* const* d_in, const int* in_sizes, int n_in,
                              void* d_out, int out_size, void* d_ws, size_t ws_size,
                              hipStream_t stream) {
    const float* w1    = (const float*)d_in[0];
    const float* root1 = (const float*)d_in[1];
    const float* bias1 = (const float*)d_in[2];
    const float* w2    = (const float*)d_in[3];
    const float* root2 = (const float*)d_in[4];
    const float* bias2 = (const float*)d_in[5];
    const int*   ei    = (const int*)d_in[6];
    const int*   et    = (const int*)d_in[7];
    float* out = (float*)d_out;

    // workspace layout (4-byte units)
    float*    inv      = (float*)d_ws;                     // 400000 (doubles as cnt_nr)
    unsigned* cnt_n    = (unsigned*)(inv + 400000);        // 50000
    unsigned* node_off = cnt_n + 50000;                    // 50001
    unsigned* cursor   = node_off + 50001;                 // 50000
    unsigned* bsums    = cursor + 50000;                   // 256
    unsigned* srcr     = bsums + 256;                      // 1600000
    float*    x        = (float*)(srcr + 1600000);         // 6400000
    float*    xw       = x + 6400000;                      // 12800000

    hipMemsetAsync(inv, 0, 400000 * sizeof(unsigned), stream);

    const int nb = (NN + 255) / 256;  // 196 scan chunks

    count_kernel<<<(EE + 255) / 256, 256, 0, stream>>>(ei, et, (unsigned*)inv);
    inv_total_kernel<<<nb, 256, 0, stream>>>((unsigned*)inv, inv, cnt_n);
    scan_blocks<<<nb, 256, 0, stream>>>(cnt_n, node_off, bsums);
    scan_top<<<1, 256, 0, stream>>>(bsums, nb);
    scan_add<<<nb, 256, 0, stream>>>(node_off, bsums, cursor);
    scatter_kernel<<<(EE + 255) / 256, 256, 0, stream>>>(ei, et, cursor, srcr);
    l1_gather<<<(NN + 3) / 4, 256, 0, stream>>>(node_off, srcr, inv, w1, root1, bias1, x);
    xw_kernel<<<NN, 256, 0, stream>>>(x, w2, xw);
    l2_gather<<<(NN + 7) / 8, 256, 0, stream>>>(node_off, srcr, inv, xw, x, root2, bias2, out);
}

// Round 3
// 593.068 us; speedup vs baseline: 2.0311x; 1.2201x over previous
//
#include <hip/hip_runtime.h>
#include <math.h>

#define NN 50000
#define RR 8
#define HH 128
#define LL 32
#define EE 1600000

// ---- count edges per (dst, relation) ----
__global__ void count_kernel(const int* __restrict__ ei, const int* __restrict__ et,
                             unsigned* __restrict__ cnt) {
    int e = blockIdx.x * blockDim.x + threadIdx.x;
    if (e >= EE) return;
    int dst = ei[EE + e];
    int r = et[e];
    atomicAdd(&cnt[dst * RR + r], 1u);
}

// ---- per node: inv[n,r] = 1/max(cnt,1) in place; cnt_n[n] = total degree ----
__global__ void inv_total_kernel(unsigned* __restrict__ cnt_nr, float* __restrict__ inv,
                                 unsigned* __restrict__ cnt_n) {
    int n = blockIdx.x * blockDim.x + threadIdx.x;
    if (n >= NN) return;
    unsigned tot = 0;
#pragma unroll
    for (int r = 0; r < RR; ++r) {
        unsigned c = cnt_nr[n * RR + r];
        tot += c;
        inv[n * RR + r] = c ? 1.0f / (float)c : 0.0f;
    }
    cnt_n[n] = tot;
}

// ---- exclusive scan, 3 kernels (chunks of 256) ----
__global__ void scan_blocks(const unsigned* __restrict__ cnt_n, unsigned* __restrict__ node_off,
                            unsigned* __restrict__ bsums) {
    __shared__ unsigned s[256];
    int t = threadIdx.x, g = blockIdx.x * 256 + t;
    unsigned v = (g < NN) ? cnt_n[g] : 0;
    s[t] = v; __syncthreads();
    for (int off = 1; off < 256; off <<= 1) {
        unsigned u = (t >= off) ? s[t - off] : 0; __syncthreads();
        if (t >= off) s[t] += u; __syncthreads();
    }
    if (g < NN) node_off[g] = s[t] - v;
    if (t == 255) bsums[blockIdx.x] = s[255];
}

__global__ void scan_top(unsigned* __restrict__ bsums, int nb) {
    __shared__ unsigned s[256];
    int t = threadIdx.x;
    unsigned v = (t < nb) ? bsums[t] : 0;
    s[t] = v; __syncthreads();
    for (int off = 1; off < 256; off <<= 1) {
        unsigned u = (t >= off) ? s[t - off] : 0; __syncthreads();
        if (t >= off) s[t] += u; __syncthreads();
    }
    if (t < nb) bsums[t] = s[t] - v;
}

__global__ void scan_add(unsigned* __restrict__ node_off, const unsigned* __restrict__ bsums,
                         unsigned* __restrict__ cursor) {
    int g = blockIdx.x * 256 + threadIdx.x;
    if (g < NN) {
        unsigned o = node_off[g] + bsums[g >> 8];
        node_off[g] = o;
        cursor[g] = o;
    }
    if (g == 0) node_off[NN] = EE;
}

// ---- scatter edges into dst-sorted order, packed key src | (r<<16) ----
__global__ void scatter_kernel(const int* __restrict__ ei, const int* __restrict__ et,
                               unsigned* __restrict__ cursor, unsigned* __restrict__ srcr) {
    int e = blockIdx.x * blockDim.x + threadIdx.x;
    if (e >= EE) return;
    int src = ei[e], dst = ei[EE + e], r = et[e];
    unsigned p = atomicAdd(&cursor[dst], 1u);
    srcr[p] = (unsigned)src | ((unsigned)r << 16);
}

// ---- layer 1: one wave per node; 2 edges/iter (half-waves) x2 unroll ----
__global__ __launch_bounds__(256) void l1_gather(const unsigned* __restrict__ node_off,
                                                 const unsigned* __restrict__ srcr,
                                                 const float* __restrict__ inv,
                                                 const float* __restrict__ w1,
                                                 const float* __restrict__ root1,
                                                 const float* __restrict__ bias1,
                                                 float* __restrict__ x) {
    int wid = threadIdx.x >> 6, lane = threadIdx.x & 63;
    int n = blockIdx.x * 4 + wid;
    if (n >= NN) return;
    int half = lane >> 5;   // which edge of the pair
    int hl = lane & 31;     // float4 chunk index: h = hl*4
    int beg = node_off[n], end = node_off[n + 1];
    float ax = 0.f, ay = 0.f, az = 0.f, aw = 0.f;
    int e = beg + half;
    for (; e + 2 < end; e += 4) {
        unsigned k0 = srcr[e], k1 = srcr[e + 2];
        unsigned r0 = k0 >> 16, s0 = k0 & 0xFFFFu;
        unsigned r1 = k1 >> 16, s1 = k1 & 0xFFFFu;
        float c0 = inv[n * RR + r0];
        float c1 = inv[n * RR + r1];
        float4 v0 = ((const float4*)(w1 + ((size_t)r0 * NN + s0) * HH))[hl];
        float4 v1 = ((const float4*)(w1 + ((size_t)r1 * NN + s1) * HH))[hl];
        ax += v0.x * c0 + v1.x * c1;
        ay += v0.y * c0 + v1.y * c1;
        az += v0.z * c0 + v1.z * c1;
        aw += v0.w * c0 + v1.w * c1;
    }
    if (e < end) {
        unsigned k0 = srcr[e];
        unsigned r0 = k0 >> 16, s0 = k0 & 0xFFFFu;
        float c0 = inv[n * RR + r0];
        float4 v0 = ((const float4*)(w1 + ((size_t)r0 * NN + s0) * HH))[hl];
        ax += v0.x * c0; ay += v0.y * c0; az += v0.z * c0; aw += v0.w * c0;
    }
    // combine the two halves
    ax += __shfl_xor(ax, 32);
    ay += __shfl_xor(ay, 32);
    az += __shfl_xor(az, 32);
    aw += __shfl_xor(aw, 32);
    if (half == 0) {
        float4 rt = ((const float4*)(root1 + (size_t)n * HH))[hl];
        float4 bs = ((const float4*)bias1)[hl];
        float4 res;
        res.x = ax + rt.x + bs.x; res.x = res.x > 0.f ? res.x : 0.f;
        res.y = ay + rt.y + bs.y; res.y = res.y > 0.f ? res.y : 0.f;
        res.z = az + rt.z + bs.z; res.z = res.z > 0.f ? res.z : 0.f;
        res.w = aw + rt.w + bs.w; res.w = res.w > 0.f ? res.w : 0.f;
        ((float4*)(x + (size_t)n * HH))[hl] = res;
    }
}

// ---- xw[n,r,l] = sum_h x[n,h] * w2[r,h,l]; 4 nodes per 256-thread block ----
__global__ __launch_bounds__(256) void xw_kernel(const float* __restrict__ x,
                                                 const float* __restrict__ w2,
                                                 float* __restrict__ xw) {
    __shared__ float xs[4][HH];
    int n0 = blockIdx.x * 4;
    int t = threadIdx.x;
    ((float2*)xs)[t] = ((const float2*)(x + (size_t)n0 * HH))[t];  // 4 contiguous rows
    __syncthreads();
    int sub = t >> 6, u = t & 63, r = u >> 3, lq = u & 7;
    const float4* wp = (const float4*)(w2 + r * HH * LL) + lq;
    float ax = 0.f, ay = 0.f, az = 0.f, aw = 0.f;
#pragma unroll 8
    for (int h = 0; h < HH; ++h) {
        float xv = xs[sub][h];
        float4 w = wp[h * 8];
        ax += xv * w.x; ay += xv * w.y; az += xv * w.z; aw += xv * w.w;
    }
    float4 res = {ax, ay, az, aw};
    ((float4*)xw)[(size_t)(n0 + sub) * 64 + u] = res;
}

// ---- layer 2: one wave per node; 2 edges/iter x2 unroll; fused root2+bias2+sigmoid ----
__global__ __launch_bounds__(256) void l2_gather(const unsigned* __restrict__ node_off,
                                                 const unsigned* __restrict__ srcr,
                                                 const float* __restrict__ inv,
                                                 const float* __restrict__ xw,
                                                 const float* __restrict__ x,
                                                 const float* __restrict__ root2,
                                                 const float* __restrict__ bias2,
                                                 float* __restrict__ out) {
    int wid = threadIdx.x >> 6, lane = threadIdx.x & 63;
    int n = blockIdx.x * 4 + wid;
    if (n >= NN) return;
    int half = lane >> 5;
    int l = lane & 31;
    int beg = node_off[n], end = node_off[n + 1];
    float acc = 0.f;
    int e = beg + half;
    for (; e + 2 < end; e += 4) {
        unsigned k0 = srcr[e], k1 = srcr[e + 2];
        unsigned r0 = k0 >> 16, s0 = k0 & 0xFFFFu;
        unsigned r1 = k1 >> 16, s1 = k1 & 0xFFFFu;
        float c0 = inv[n * RR + r0];
        float c1 = inv[n * RR + r1];
        float v0 = xw[((size_t)s0 * RR + r0) * LL + l];
        float v1 = xw[((size_t)s1 * RR + r1) * LL + l];
        acc += v0 * c0 + v1 * c1;
    }
    if (e < end) {
        unsigned k0 = srcr[e];
        unsigned r0 = k0 >> 16, s0 = k0 & 0xFFFFu;
        acc += xw[((size_t)s0 * RR + r0) * LL + l] * inv[n * RR + r0];
    }
    // root2 dot: half 0 covers h 0..63, half 1 covers h 64..127
    const float* xp = x + (size_t)n * HH + half * 64;
    const float* rp = root2 + (size_t)half * 64 * LL + l;
#pragma unroll 8
    for (int h = 0; h < 64; ++h) acc += xp[h] * rp[h * LL];
    acc += __shfl_xor(acc, 32);
    if (half == 0) {
        float z = acc + bias2[l];
        out[n * LL + l] = 1.0f / (1.0f + expf(-z));
    }
}

extern "C" void kernel_launch(void* const* d_in, const int* in_sizes, int n_in,
                              void* d_out, int out_size, void* d_ws, size_t ws_size,
                              hipStream_t stream) {
    const float* w1    = (const float*)d_in[0];
    const float* root1 = (const float*)d_in[1];
    const float* bias1 = (const float*)d_in[2];
    const float* w2    = (const float*)d_in[3];
    const float* root2 = (const float*)d_in[4];
    const float* bias2 = (const float*)d_in[5];
    const int*   ei    = (const int*)d_in[6];
    const int*   et    = (const int*)d_in[7];
    float* out = (float*)d_out;

    // workspace layout (4-byte units)
    float*    inv      = (float*)d_ws;                     // 400000 (doubles as cnt_nr)
    unsigned* cnt_n    = (unsigned*)(inv + 400000);        // 50000
    unsigned* node_off = cnt_n + 50000;                    // 50001
    unsigned* cursor   = node_off + 50001;                 // 50000
    unsigned* bsums    = cursor + 50000;                   // 256
    unsigned* srcr     = bsums + 256;                      // 1600000
    float*    x        = (float*)(srcr + 1600000);         // 6400000
    float*    xw       = x + 6400000;                      // 12800000

    hipMemsetAsync(inv, 0, 400000 * sizeof(unsigned), stream);

    const int nb = (NN + 255) / 256;  // 196 scan chunks

    count_kernel<<<(EE + 255) / 256, 256, 0, stream>>>(ei, et, (unsigned*)inv);
    inv_total_kernel<<<nb, 256, 0, stream>>>((unsigned*)inv, inv, cnt_n);
    scan_blocks<<<nb, 256, 0, stream>>>(cnt_n, node_off, bsums);
    scan_top<<<1, 256, 0, stream>>>(bsums, nb);
    scan_add<<<nb, 256, 0, stream>>>(node_off, bsums, cursor);
    scatter_kernel<<<(EE + 255) / 256, 256, 0, stream>>>(ei, et, cursor, srcr);
    l1_gather<<<(NN + 3) / 4, 256, 0, stream>>>(node_off, srcr, inv, w1, root1, bias1, x);
    xw_kernel<<<NN / 4, 256, 0, stream>>>(x, w2, xw);
    l2_gather<<<(NN + 3) / 4, 256, 0, stream>>>(node_off, srcr, inv, xw, x, root2, bias2, out);
}

// Round 4
// 451.691 us; speedup vs baseline: 2.6669x; 1.3130x over previous
//
#include <hip/hip_runtime.h>
#include <math.h>

#define NN 50000
#define RR 8
#define HH 128
#define LL 32
#define EE 1600000

#define FMA4(A, V, C) { A.x += (V).x*(C); A.y += (V).y*(C); A.z += (V).z*(C); A.w += (V).w*(C); }

// ---- count edges per (dst, relation) ----
__global__ void count_kernel(const int* __restrict__ ei, const int* __restrict__ et,
                             unsigned* __restrict__ cnt) {
    int e = blockIdx.x * blockDim.x + threadIdx.x;
    if (e >= EE) return;
    int dst = ei[EE + e];
    int r = et[e];
    atomicAdd(&cnt[dst * RR + r], 1u);
}

// ---- per node: inv[n,r] = 1/max(cnt,1) in place; cnt_n[n] = total degree ----
__global__ void inv_total_kernel(unsigned* __restrict__ cnt_nr, float* __restrict__ inv,
                                 unsigned* __restrict__ cnt_n) {
    int n = blockIdx.x * blockDim.x + threadIdx.x;
    if (n >= NN) return;
    unsigned tot = 0;
#pragma unroll
    for (int r = 0; r < RR; ++r) {
        unsigned c = cnt_nr[n * RR + r];
        tot += c;
        inv[n * RR + r] = c ? 1.0f / (float)c : 0.0f;
    }
    cnt_n[n] = tot;
}

// ---- exclusive scan, 3 kernels (chunks of 256) ----
__global__ void scan_blocks(const unsigned* __restrict__ cnt_n, unsigned* __restrict__ node_off,
                            unsigned* __restrict__ bsums) {
    __shared__ unsigned s[256];
    int t = threadIdx.x, g = blockIdx.x * 256 + t;
    unsigned v = (g < NN) ? cnt_n[g] : 0;
    s[t] = v; __syncthreads();
    for (int off = 1; off < 256; off <<= 1) {
        unsigned u = (t >= off) ? s[t - off] : 0; __syncthreads();
        if (t >= off) s[t] += u; __syncthreads();
    }
    if (g < NN) node_off[g] = s[t] - v;
    if (t == 255) bsums[blockIdx.x] = s[255];
}

__global__ void scan_top(unsigned* __restrict__ bsums, int nb) {
    __shared__ unsigned s[256];
    int t = threadIdx.x;
    unsigned v = (t < nb) ? bsums[t] : 0;
    s[t] = v; __syncthreads();
    for (int off = 1; off < 256; off <<= 1) {
        unsigned u = (t >= off) ? s[t - off] : 0; __syncthreads();
        if (t >= off) s[t] += u; __syncthreads();
    }
    if (t < nb) bsums[t] = s[t] - v;
}

__global__ void scan_add(unsigned* __restrict__ node_off, const unsigned* __restrict__ bsums,
                         unsigned* __restrict__ cursor, unsigned* __restrict__ srcr) {
    int g = blockIdx.x * 256 + threadIdx.x;
    if (g < NN) {
        unsigned o = node_off[g] + bsums[g >> 8];
        node_off[g] = o;
        cursor[g] = o;
    }
    if (g == 0) node_off[NN] = EE;
    if (g < 8) srcr[EE + g] = 0;  // dummy keys for uniform tails
}

// ---- scatter edges into dst-sorted order, packed key src | (r<<16) ----
__global__ void scatter_kernel(const int* __restrict__ ei, const int* __restrict__ et,
                               unsigned* __restrict__ cursor, unsigned* __restrict__ srcr) {
    int e = blockIdx.x * blockDim.x + threadIdx.x;
    if (e >= EE) return;
    int src = ei[e], dst = ei[EE + e], r = et[e];
    unsigned p = atomicAdd(&cursor[dst], 1u);
    srcr[p] = (unsigned)src | ((unsigned)r << 16);
}

// ---- layer 1: one wave per node; quarter-wave per edge, 2 slots -> 8 rows in flight ----
__global__ __launch_bounds__(256) void l1_gather(const unsigned* __restrict__ node_off,
                                                 const unsigned* __restrict__ srcr,
                                                 const float* __restrict__ inv,
                                                 const float* __restrict__ w1,
                                                 const float* __restrict__ root1,
                                                 const float* __restrict__ bias1,
                                                 float* __restrict__ x) {
    int wid = threadIdx.x >> 6, lane = threadIdx.x & 63;
    int n = blockIdx.x * 4 + wid;
    if (n >= NN) return;
    int q = lane >> 4, ql = lane & 15;
    int beg = node_off[n], end = node_off[n + 1];
    int cnt = end - beg;
    int nfull = cnt >> 3;                    // full 8-edge iterations (uniform)
    float myinv = inv[n * RR + (lane & 7)];  // lanes 0..7 hold the 8 inv values
    float4 a0 = {0.f, 0.f, 0.f, 0.f}, a1 = {0.f, 0.f, 0.f, 0.f};
    int e = beg + q;
    for (int it = 0; it < nfull; ++it, e += 8) {
        unsigned k0 = srcr[e], k1 = srcr[e + 4];
        unsigned s0 = k0 & 0xFFFFu, r0 = k0 >> 16;
        unsigned s1 = k1 & 0xFFFFu, r1 = k1 >> 16;
        float c0 = __shfl(myinv, (int)r0);
        float c1 = __shfl(myinv, (int)r1);
        const float4* p0 = (const float4*)(w1 + ((size_t)r0 * NN + s0) * HH);
        const float4* p1 = (const float4*)(w1 + ((size_t)r1 * NN + s1) * HH);
        float4 v00 = p0[ql], v01 = p0[ql + 16];
        float4 v10 = p1[ql], v11 = p1[ql + 16];
        FMA4(a0, v00, c0); FMA4(a1, v01, c0);
        FMA4(a0, v10, c1); FMA4(a1, v11, c1);
    }
    {   // tail: executed by all lanes (shfl uniform), loads guarded
        unsigned k0 = srcr[e], k1 = srcr[e + 4];   // safe: srcr padded +8
        bool val0 = e < end, val1 = (e + 4) < end;
        unsigned s0 = k0 & 0xFFFFu, r0 = k0 >> 16;
        unsigned s1 = k1 & 0xFFFFu, r1 = k1 >> 16;
        float c0 = __shfl(myinv, (int)r0);
        float c1 = __shfl(myinv, (int)r1);
        if (val0) {
            const float4* p0 = (const float4*)(w1 + ((size_t)r0 * NN + s0) * HH);
            float4 v00 = p0[ql], v01 = p0[ql + 16];
            FMA4(a0, v00, c0); FMA4(a1, v01, c0);
        }
        if (val1) {
            const float4* p1 = (const float4*)(w1 + ((size_t)r1 * NN + s1) * HH);
            float4 v10 = p1[ql], v11 = p1[ql + 16];
            FMA4(a0, v10, c1); FMA4(a1, v11, c1);
        }
    }
#define RED(c) { c += __shfl_xor(c, 16); c += __shfl_xor(c, 32); }
    RED(a0.x); RED(a0.y); RED(a0.z); RED(a0.w);
    RED(a1.x); RED(a1.y); RED(a1.z); RED(a1.w);
#undef RED
    if (q == 0) {
        const float4* rt = (const float4*)(root1 + (size_t)n * HH);
        const float4* bs = (const float4*)bias1;
        float4 rA = rt[ql], rB = rt[ql + 16];
        float4 bA = bs[ql], bB = bs[ql + 16];
        float4 o0, o1;
        o0.x = fmaxf(a0.x + rA.x + bA.x, 0.f);
        o0.y = fmaxf(a0.y + rA.y + bA.y, 0.f);
        o0.z = fmaxf(a0.z + rA.z + bA.z, 0.f);
        o0.w = fmaxf(a0.w + rA.w + bA.w, 0.f);
        o1.x = fmaxf(a1.x + rB.x + bB.x, 0.f);
        o1.y = fmaxf(a1.y + rB.y + bB.y, 0.f);
        o1.z = fmaxf(a1.z + rB.z + bB.z, 0.f);
        o1.w = fmaxf(a1.w + rB.w + bB.w, 0.f);
        ((float4*)(x + (size_t)n * HH))[ql] = o0;
        ((float4*)(x + (size_t)n * HH))[ql + 16] = o1;
    }
}

// ---- xw: register-blocked GEMM. 32 nodes/block, wave owns 8 nodes, lane owns 4 cols ----
__global__ __launch_bounds__(256) void xw_kernel(const float* __restrict__ x,
                                                 const float* __restrict__ w2,
                                                 float* __restrict__ xw) {
    __shared__ float xsT[HH][32];          // 16 KB, x tile transposed
    int t = threadIdx.x;
    int n0 = blockIdx.x * 32;
    {
        int n = t & 31, qq = t >> 5;       // qq: 8 chunks of 16 floats
        int nn = n0 + n; if (nn >= NN) nn = NN - 1;
        const float4* xp = (const float4*)(x + (size_t)nn * HH) + qq * 4;
#pragma unroll
        for (int j = 0; j < 4; ++j) {
            float4 v = xp[j];
            int h = qq * 16 + j * 4;
            xsT[h][n] = v.x; xsT[h + 1][n] = v.y; xsT[h + 2][n] = v.z; xsT[h + 3][n] = v.w;
        }
    }
    __syncthreads();
    int wid = t >> 6, lane = t & 63;
    int nb = wid * 8;
    const float4* wp = (const float4*)w2 + (lane >> 3) * (HH * 8) + (lane & 7);
    float4 acc0 = {0,0,0,0}, acc1 = {0,0,0,0}, acc2 = {0,0,0,0}, acc3 = {0,0,0,0};
    float4 acc4 = {0,0,0,0}, acc5 = {0,0,0,0}, acc6 = {0,0,0,0}, acc7 = {0,0,0,0};
#pragma unroll 8
    for (int h = 0; h < HH; ++h) {
        float4 w = wp[h * 8];
        float4 xa = *(const float4*)(&xsT[h][nb]);
        float4 xb = *(const float4*)(&xsT[h][nb + 4]);
        FMA4(acc0, w, xa.x); FMA4(acc1, w, xa.y); FMA4(acc2, w, xa.z); FMA4(acc3, w, xa.w);
        FMA4(acc4, w, xb.x); FMA4(acc5, w, xb.y); FMA4(acc6, w, xb.z); FMA4(acc7, w, xb.w);
    }
    float4* op = (float4*)xw + (size_t)(n0 + nb) * 64 + lane;
    int rem = NN - (n0 + nb);
    if (rem > 0) op[0 * 64] = acc0;
    if (rem > 1) op[1 * 64] = acc1;
    if (rem > 2) op[2 * 64] = acc2;
    if (rem > 3) op[3 * 64] = acc3;
    if (rem > 4) op[4 * 64] = acc4;
    if (rem > 5) op[5 * 64] = acc5;
    if (rem > 6) op[6 * 64] = acc6;
    if (rem > 7) op[7 * 64] = acc7;
}

// ---- layer 2: one wave per node; 2 edges/iter x2 unroll; fused root2+bias2+sigmoid ----
__global__ __launch_bounds__(256) void l2_gather(const unsigned* __restrict__ node_off,
                                                 const unsigned* __restrict__ srcr,
                                                 const float* __restrict__ inv,
                                                 const float* __restrict__ xw,
                                                 const float* __restrict__ x,
                                                 const float* __restrict__ root2,
                                                 const float* __restrict__ bias2,
                                                 float* __restrict__ out) {
    int wid = threadIdx.x >> 6, lane = threadIdx.x & 63;
    int n = blockIdx.x * 4 + wid;
    if (n >= NN) return;
    int half = lane >> 5;
    int l = lane & 31;
    int beg = node_off[n], end = node_off[n + 1];
    float acc = 0.f;
    int e = beg + half;
    for (; e + 2 < end; e += 4) {
        unsigned k0 = srcr[e], k1 = srcr[e + 2];
        unsigned r0 = k0 >> 16, s0 = k0 & 0xFFFFu;
        unsigned r1 = k1 >> 16, s1 = k1 & 0xFFFFu;
        float c0 = inv[n * RR + r0];
        float c1 = inv[n * RR + r1];
        float v0 = xw[((size_t)s0 * RR + r0) * LL + l];
        float v1 = xw[((size_t)s1 * RR + r1) * LL + l];
        acc += v0 * c0 + v1 * c1;
    }
    if (e < end) {
        unsigned k0 = srcr[e];
        unsigned r0 = k0 >> 16, s0 = k0 & 0xFFFFu;
        acc += xw[((size_t)s0 * RR + r0) * LL + l] * inv[n * RR + r0];
    }
    const float* xp = x + (size_t)n * HH + half * 64;
    const float* rp = root2 + (size_t)half * 64 * LL + l;
#pragma unroll 8
    for (int h = 0; h < 64; ++h) acc += xp[h] * rp[h * LL];
    acc += __shfl_xor(acc, 32);
    if (half == 0) {
        float z = acc + bias2[l];
        out[n * LL + l] = 1.0f / (1.0f + expf(-z));
    }
}

extern "C" void kernel_launch(void* const* d_in, const int* in_sizes, int n_in,
                              void* d_out, int out_size, void* d_ws, size_t ws_size,
                              hipStream_t stream) {
    const float* w1    = (const float*)d_in[0];
    const float* root1 = (const float*)d_in[1];
    const float* bias1 = (const float*)d_in[2];
    const float* w2    = (const float*)d_in[3];
    const float* root2 = (const float*)d_in[4];
    const float* bias2 = (const float*)d_in[5];
    const int*   ei    = (const int*)d_in[6];
    const int*   et    = (const int*)d_in[7];
    float* out = (float*)d_out;

    // workspace layout (4-byte words, all 16B-aligned)
    float*    inv      = (float*)d_ws;                     // @0        400000 (doubles as cnt_nr)
    unsigned* cnt_n    = (unsigned*)(inv + 400000);        // @400000   50000
    unsigned* node_off = cnt_n + 50000;                    // @450000   50001 (pad to 50004)
    unsigned* cursor   = node_off + 50004;                 // @500004   50000
    unsigned* bsums    = cursor + 50000;                   // @550004   256
    unsigned* srcr     = bsums + 256;                      // @550260   1600008 (pad to 1600012)
    float*    x        = (float*)(srcr + 1600012);         // @2150272  6400000
    float*    xw       = x + 6400000;                      // @8550272  12800000

    hipMemsetAsync(inv, 0, 400000 * sizeof(unsigned), stream);

    const int nb = (NN + 255) / 256;  // 196 scan chunks

    count_kernel<<<(EE + 255) / 256, 256, 0, stream>>>(ei, et, (unsigned*)inv);
    inv_total_kernel<<<nb, 256, 0, stream>>>((unsigned*)inv, inv, cnt_n);
    scan_blocks<<<nb, 256, 0, stream>>>(cnt_n, node_off, bsums);
    scan_top<<<1, 256, 0, stream>>>(bsums, nb);
    scan_add<<<nb, 256, 0, stream>>>(node_off, bsums, cursor, srcr);
    scatter_kernel<<<(EE + 255) / 256, 256, 0, stream>>>(ei, et, cursor, srcr);
    l1_gather<<<(NN + 3) / 4, 256, 0, stream>>>(node_off, srcr, inv, w1, root1, bias1, x);
    xw_kernel<<<(NN + 31) / 32, 256, 0, stream>>>(x, w2, xw);
    l2_gather<<<(NN + 3) / 4, 256, 0, stream>>>(node_off, srcr, inv, xw, x, root2, bias2, out);
}

// Round 5
// 429.789 us; speedup vs baseline: 2.8028x; 1.0510x over previous
//
#include <hip/hip_runtime.h>
#include <math.h>

#define NN 50000
#define RR 8
#define HH 128
#define LL 32
#define EE 1600000

#define FMA4(A, V, C) { A.x += (V).x*(C); A.y += (V).y*(C); A.z += (V).z*(C); A.w += (V).w*(C); }

// ---- count edges per (dst, relation) ----
__global__ void count_kernel(const int* __restrict__ ei, const int* __restrict__ et,
                             unsigned* __restrict__ cnt) {
    int e = blockIdx.x * blockDim.x + threadIdx.x;
    if (e >= EE) return;
    int dst = ei[EE + e];
    int r = et[e];
    atomicAdd(&cnt[dst * RR + r], 1u);
}

// ---- fused: inv = 1/max(cnt,1) in place; per-node totals; block-local scan ----
__global__ void scan_blocks(unsigned* __restrict__ cnt_nr, float* __restrict__ inv,
                            unsigned* __restrict__ node_off, unsigned* __restrict__ bsums) {
    __shared__ unsigned s[256];
    int t = threadIdx.x, g = blockIdx.x * 256 + t;
    unsigned tot = 0;
    if (g < NN) {
        uint4 ca = ((const uint4*)cnt_nr)[g * 2];
        uint4 cb = ((const uint4*)cnt_nr)[g * 2 + 1];
        tot = ca.x + ca.y + ca.z + ca.w + cb.x + cb.y + cb.z + cb.w;
        float4 ia, ib;
        ia.x = ca.x ? 1.f / (float)ca.x : 0.f;
        ia.y = ca.y ? 1.f / (float)ca.y : 0.f;
        ia.z = ca.z ? 1.f / (float)ca.z : 0.f;
        ia.w = ca.w ? 1.f / (float)ca.w : 0.f;
        ib.x = cb.x ? 1.f / (float)cb.x : 0.f;
        ib.y = cb.y ? 1.f / (float)cb.y : 0.f;
        ib.z = cb.z ? 1.f / (float)cb.z : 0.f;
        ib.w = cb.w ? 1.f / (float)cb.w : 0.f;
        ((float4*)inv)[g * 2] = ia;
        ((float4*)inv)[g * 2 + 1] = ib;
    }
    s[t] = tot; __syncthreads();
    for (int off = 1; off < 256; off <<= 1) {
        unsigned u = (t >= off) ? s[t - off] : 0; __syncthreads();
        if (t >= off) s[t] += u; __syncthreads();
    }
    if (g < NN) node_off[g] = s[t] - tot;
    if (t == 255) bsums[blockIdx.x] = s[255];
}

__global__ void scan_top(unsigned* __restrict__ bsums, int nb) {
    __shared__ unsigned s[256];
    int t = threadIdx.x;
    unsigned v = (t < nb) ? bsums[t] : 0;
    s[t] = v; __syncthreads();
    for (int off = 1; off < 256; off <<= 1) {
        unsigned u = (t >= off) ? s[t - off] : 0; __syncthreads();
        if (t >= off) s[t] += u; __syncthreads();
    }
    if (t < nb) bsums[t] = s[t] - v;
}

__global__ void scan_add(unsigned* __restrict__ node_off, const unsigned* __restrict__ bsums,
                         unsigned* __restrict__ cursor, unsigned* __restrict__ srcr) {
    int g = blockIdx.x * 256 + threadIdx.x;
    if (g < NN) {
        unsigned o = node_off[g] + bsums[g >> 8];
        node_off[g] = o;
        cursor[g] = o;
    }
    if (g == 0) node_off[NN] = EE;
    if (g < 16) srcr[EE + g] = 0;  // dummy keys for uniform tails
}

// ---- scatter edges into dst-sorted order, packed key src | (r<<16) ----
__global__ void scatter_kernel(const int* __restrict__ ei, const int* __restrict__ et,
                               unsigned* __restrict__ cursor, unsigned* __restrict__ srcr) {
    int e = blockIdx.x * blockDim.x + threadIdx.x;
    if (e >= EE) return;
    int src = ei[e], dst = ei[EE + e], r = et[e];
    unsigned p = atomicAdd(&cursor[dst], 1u);
    srcr[p] = (unsigned)src | ((unsigned)r << 16);
}

// ---- layer 1: wave per node; quarter-wave per edge, 4 slots -> 8 row loads in flight ----
__global__ __launch_bounds__(256) void l1_gather(const unsigned* __restrict__ node_off,
                                                 const unsigned* __restrict__ srcr,
                                                 const float* __restrict__ inv,
                                                 const float* __restrict__ w1,
                                                 const float* __restrict__ root1,
                                                 const float* __restrict__ bias1,
                                                 float* __restrict__ x) {
    int wid = threadIdx.x >> 6, lane = threadIdx.x & 63;
    int n = blockIdx.x * 4 + wid;
    if (n >= NN) return;
    int q = lane >> 4, ql = lane & 15;
    int beg = node_off[n], end = node_off[n + 1];
    int cnt = end - beg;
    int nfull = cnt >> 4;                    // 16 edges per full iteration
    float myinv = inv[n * RR + (lane & 7)];  // lanes 0..7 hold the 8 inv values
    float4 a0 = {0.f, 0.f, 0.f, 0.f}, a1 = {0.f, 0.f, 0.f, 0.f};
    int e = beg + q;
#pragma unroll 1
    for (int it = 0; it < nfull; ++it, e += 16) {
        unsigned k0 = srcr[e], k1 = srcr[e + 4], k2 = srcr[e + 8], k3 = srcr[e + 12];
        unsigned s0 = k0 & 0xFFFFu, r0 = k0 >> 16;
        unsigned s1 = k1 & 0xFFFFu, r1 = k1 >> 16;
        unsigned s2 = k2 & 0xFFFFu, r2 = k2 >> 16;
        unsigned s3 = k3 & 0xFFFFu, r3 = k3 >> 16;
        float c0 = __shfl(myinv, (int)r0);
        float c1 = __shfl(myinv, (int)r1);
        float c2 = __shfl(myinv, (int)r2);
        float c3 = __shfl(myinv, (int)r3);
        const float4* p0 = (const float4*)(w1 + ((size_t)r0 * NN + s0) * HH);
        const float4* p1 = (const float4*)(w1 + ((size_t)r1 * NN + s1) * HH);
        const float4* p2 = (const float4*)(w1 + ((size_t)r2 * NN + s2) * HH);
        const float4* p3 = (const float4*)(w1 + ((size_t)r3 * NN + s3) * HH);
        float4 v00 = p0[ql], v01 = p0[ql + 16];
        float4 v10 = p1[ql], v11 = p1[ql + 16];
        float4 v20 = p2[ql], v21 = p2[ql + 16];
        float4 v30 = p3[ql], v31 = p3[ql + 16];
        FMA4(a0, v00, c0); FMA4(a1, v01, c0);
        FMA4(a0, v10, c1); FMA4(a1, v11, c1);
        FMA4(a0, v20, c2); FMA4(a1, v21, c2);
        FMA4(a0, v30, c3); FMA4(a1, v31, c3);
    }
    {   // tail: up to 15 edges; shfl wave-uniform, loads guarded (srcr padded +16)
        unsigned k0 = srcr[e], k1 = srcr[e + 4], k2 = srcr[e + 8], k3 = srcr[e + 12];
        unsigned s0 = k0 & 0xFFFFu, r0 = k0 >> 16;
        unsigned s1 = k1 & 0xFFFFu, r1 = k1 >> 16;
        unsigned s2 = k2 & 0xFFFFu, r2 = k2 >> 16;
        unsigned s3 = k3 & 0xFFFFu, r3 = k3 >> 16;
        float c0 = __shfl(myinv, (int)r0);
        float c1 = __shfl(myinv, (int)r1);
        float c2 = __shfl(myinv, (int)r2);
        float c3 = __shfl(myinv, (int)r3);
        if (e < end) {
            const float4* p = (const float4*)(w1 + ((size_t)r0 * NN + s0) * HH);
            float4 va = p[ql], vb = p[ql + 16];
            FMA4(a0, va, c0); FMA4(a1, vb, c0);
        }
        if (e + 4 < end) {
            const float4* p = (const float4*)(w1 + ((size_t)r1 * NN + s1) * HH);
            float4 va = p[ql], vb = p[ql + 16];
            FMA4(a0, va, c1); FMA4(a1, vb, c1);
        }
        if (e + 8 < end) {
            const float4* p = (const float4*)(w1 + ((size_t)r2 * NN + s2) * HH);
            float4 va = p[ql], vb = p[ql + 16];
            FMA4(a0, va, c2); FMA4(a1, vb, c2);
        }
        if (e + 12 < end) {
            const float4* p = (const float4*)(w1 + ((size_t)r3 * NN + s3) * HH);
            float4 va = p[ql], vb = p[ql + 16];
            FMA4(a0, va, c3); FMA4(a1, vb, c3);
        }
    }
#define RED(c) { c += __shfl_xor(c, 16); c += __shfl_xor(c, 32); }
    RED(a0.x); RED(a0.y); RED(a0.z); RED(a0.w);
    RED(a1.x); RED(a1.y); RED(a1.z); RED(a1.w);
#undef RED
    if (q == 0) {
        const float4* rt = (const float4*)(root1 + (size_t)n * HH);
        const float4* bs = (const float4*)bias1;
        float4 rA = rt[ql], rB = rt[ql + 16];
        float4 bA = bs[ql], bB = bs[ql + 16];
        float4 o0, o1;
        o0.x = fmaxf(a0.x + rA.x + bA.x, 0.f);
        o0.y = fmaxf(a0.y + rA.y + bA.y, 0.f);
        o0.z = fmaxf(a0.z + rA.z + bA.z, 0.f);
        o0.w = fmaxf(a0.w + rA.w + bA.w, 0.f);
        o1.x = fmaxf(a1.x + rB.x + bB.x, 0.f);
        o1.y = fmaxf(a1.y + rB.y + bB.y, 0.f);
        o1.z = fmaxf(a1.z + rB.z + bB.z, 0.f);
        o1.w = fmaxf(a1.w + rB.w + bB.w, 0.f);
        ((float4*)(x + (size_t)n * HH))[ql] = o0;
        ((float4*)(x + (size_t)n * HH))[ql + 16] = o1;
    }
}

// ---- xw: register-blocked GEMM. 32 nodes/block, wave owns 8 nodes, lane owns 4 cols ----
__global__ __launch_bounds__(256) void xw_kernel(const float* __restrict__ x,
                                                 const float* __restrict__ w2,
                                                 float* __restrict__ xw) {
    __shared__ float xsT[HH][32];          // 16 KB, x tile transposed
    int t = threadIdx.x;
    int n0 = blockIdx.x * 32;
    {
        int n = t & 31, qq = t >> 5;       // qq: 8 chunks of 16 floats
        int nn = n0 + n; if (nn >= NN) nn = NN - 1;
        const float4* xp = (const float4*)(x + (size_t)nn * HH) + qq * 4;
#pragma unroll
        for (int j = 0; j < 4; ++j) {
            float4 v = xp[j];
            int h = qq * 16 + j * 4;
            xsT[h][n] = v.x; xsT[h + 1][n] = v.y; xsT[h + 2][n] = v.z; xsT[h + 3][n] = v.w;
        }
    }
    __syncthreads();
    int wid = t >> 6, lane = t & 63;
    int nb = wid * 8;
    const float4* wp = (const float4*)w2 + (lane >> 3) * (HH * 8) + (lane & 7);
    float4 acc0 = {0,0,0,0}, acc1 = {0,0,0,0}, acc2 = {0,0,0,0}, acc3 = {0,0,0,0};
    float4 acc4 = {0,0,0,0}, acc5 = {0,0,0,0}, acc6 = {0,0,0,0}, acc7 = {0,0,0,0};
#pragma unroll 8
    for (int h = 0; h < HH; ++h) {
        float4 w = wp[h * 8];
        float4 xa = *(const float4*)(&xsT[h][nb]);
        float4 xb = *(const float4*)(&xsT[h][nb + 4]);
        FMA4(acc0, w, xa.x); FMA4(acc1, w, xa.y); FMA4(acc2, w, xa.z); FMA4(acc3, w, xa.w);
        FMA4(acc4, w, xb.x); FMA4(acc5, w, xb.y); FMA4(acc6, w, xb.z); FMA4(acc7, w, xb.w);
    }
    float4* op = (float4*)xw + (size_t)(n0 + nb) * 64 + lane;
    int rem = NN - (n0 + nb);
    if (rem > 0) op[0 * 64] = acc0;
    if (rem > 1) op[1 * 64] = acc1;
    if (rem > 2) op[2 * 64] = acc2;
    if (rem > 3) op[3 * 64] = acc3;
    if (rem > 4) op[4 * 64] = acc4;
    if (rem > 5) op[5 * 64] = acc5;
    if (rem > 6) op[6 * 64] = acc6;
    if (rem > 7) op[7 * 64] = acc7;
}

// ---- layer 2: wave per node; 8 lanes/edge, 16 edges/iter; fused root2+bias2+sigmoid ----
__global__ __launch_bounds__(256) void l2_gather(const unsigned* __restrict__ node_off,
                                                 const unsigned* __restrict__ srcr,
                                                 const float* __restrict__ inv,
                                                 const float* __restrict__ xw,
                                                 const float* __restrict__ x,
                                                 const float* __restrict__ root2,
                                                 const float* __restrict__ bias2,
                                                 float* __restrict__ out) {
    int wid = threadIdx.x >> 6, lane = threadIdx.x & 63;
    int n = blockIdx.x * 4 + wid;
    if (n >= NN) return;
    int g = lane >> 3, gl = lane & 7;
    int beg = node_off[n], end = node_off[n + 1];
    int cnt = end - beg;
    int nfull = cnt >> 4;                    // 16 edges per full iteration
    float myinv = inv[n * RR + (lane & 7)];
    float4 acc = {0.f, 0.f, 0.f, 0.f};
    int e = beg + g;
#pragma unroll 1
    for (int it = 0; it < nfull; ++it, e += 16) {
        unsigned k0 = srcr[e], k1 = srcr[e + 8];
        unsigned s0 = k0 & 0xFFFFu, r0 = k0 >> 16;
        unsigned s1 = k1 & 0xFFFFu, r1 = k1 >> 16;
        float c0 = __shfl(myinv, (int)r0);
        float c1 = __shfl(myinv, (int)r1);
        float4 v0 = ((const float4*)(xw + ((size_t)s0 * RR + r0) * LL))[gl];
        float4 v1 = ((const float4*)(xw + ((size_t)s1 * RR + r1) * LL))[gl];
        FMA4(acc, v0, c0);
        FMA4(acc, v1, c1);
    }
    {   // tail: up to 15 edges
        unsigned k0 = srcr[e], k1 = srcr[e + 8];
        unsigned s0 = k0 & 0xFFFFu, r0 = k0 >> 16;
        unsigned s1 = k1 & 0xFFFFu, r1 = k1 >> 16;
        float c0 = __shfl(myinv, (int)r0);
        float c1 = __shfl(myinv, (int)r1);
        if (e < end) {
            float4 v = ((const float4*)(xw + ((size_t)s0 * RR + r0) * LL))[gl];
            FMA4(acc, v, c0);
        }
        if (e + 8 < end) {
            float4 v = ((const float4*)(xw + ((size_t)s1 * RR + r1) * LL))[gl];
            FMA4(acc, v, c1);
        }
    }
    // root2 part in the same lane layout: group g covers h in [g*16, g*16+16)
    {
        const float* xp = x + (size_t)n * HH + g * 16;
        const float4* rp = (const float4*)root2 + g * 16 * 8 + gl;
#pragma unroll
        for (int i = 0; i < 16; ++i) {
            float xv = xp[i];
            float4 w = rp[i * 8];
            FMA4(acc, w, xv);
        }
    }
#define RED3(c) { c += __shfl_xor(c, 8); c += __shfl_xor(c, 16); c += __shfl_xor(c, 32); }
    RED3(acc.x); RED3(acc.y); RED3(acc.z); RED3(acc.w);
#undef RED3
    if (lane < 8) {
        float4 b = ((const float4*)bias2)[gl];
        float4 z;
        z.x = 1.f / (1.f + expf(-(acc.x + b.x)));
        z.y = 1.f / (1.f + expf(-(acc.y + b.y)));
        z.z = 1.f / (1.f + expf(-(acc.z + b.z)));
        z.w = 1.f / (1.f + expf(-(acc.w + b.w)));
        ((float4*)(out + (size_t)n * LL))[gl] = z;
    }
}

extern "C" void kernel_launch(void* const* d_in, const int* in_sizes, int n_in,
                              void* d_out, int out_size, void* d_ws, size_t ws_size,
                              hipStream_t stream) {
    const float* w1    = (const float*)d_in[0];
    const float* root1 = (const float*)d_in[1];
    const float* bias1 = (const float*)d_in[2];
    const float* w2    = (const float*)d_in[3];
    const float* root2 = (const float*)d_in[4];
    const float* bias2 = (const float*)d_in[5];
    const int*   ei    = (const int*)d_in[6];
    const int*   et    = (const int*)d_in[7];
    float* out = (float*)d_out;

    // workspace layout (4-byte words, x/xw 16B-aligned)
    float*    inv      = (float*)d_ws;                     // @0        400000 (doubles as cnt_nr)
    unsigned* node_off = (unsigned*)(inv + 400000);        // @400000   50001 (pad to 50004)
    unsigned* cursor   = node_off + 50004;                 // @450004   50000
    unsigned* bsums    = cursor + 50000;                   // @500004   256
    unsigned* srcr     = bsums + 256;                      // @500260   1600016
    float*    x        = (float*)(srcr + 1600016);         // @2100276  6400000
    float*    xw       = x + 6400000;                      // @8500276  12800000

    hipMemsetAsync(inv, 0, 400000 * sizeof(unsigned), stream);

    const int nb = (NN + 255) / 256;  // 196 scan chunks

    count_kernel<<<(EE + 255) / 256, 256, 0, stream>>>(ei, et, (unsigned*)inv);
    scan_blocks<<<nb, 256, 0, stream>>>((unsigned*)inv, inv, node_off, bsums);
    scan_top<<<1, 256, 0, stream>>>(bsums, nb);
    scan_add<<<nb, 256, 0, stream>>>(node_off, bsums, cursor, srcr);
    scatter_kernel<<<(EE + 255) / 256, 256, 0, stream>>>(ei, et, cursor, srcr);
    l1_gather<<<(NN + 3) / 4, 256, 0, stream>>>(node_off, srcr, inv, w1, root1, bias1, x);
    xw_kernel<<<(NN + 31) / 32, 256, 0, stream>>>(x, w2, xw);
    l2_gather<<<(NN + 3) / 4, 256, 0, stream>>>(node_off, srcr, inv, xw, x, root2, bias2, out);
}